// Round 5
// baseline (424.005 us; speedup 1.0000x reference)
//
#include <hip/hip_runtime.h>
#include <math.h>

#define D_MODEL 4096
#define N_EXP   64
#define N_ROWS  16384            // 4 * 4096
#define LN_EPS  1e-5f
#define TMB     32               // rows per block (2 row-groups of 16)
#define NBLK    (N_ROWS / TMB)   // 512 blocks -> 2 per CU
#define NSTEP   64               // K steps of BK=64 (each wave does one kb32/step)

typedef __attribute__((ext_vector_type(4))) float f32x4;
typedef __attribute__((ext_vector_type(8))) short s16x8;

struct U4 { unsigned v[4]; };

// truncating bf16 split helpers: pkt packs hi16(a) | hi16(b); residuals are exact.
__device__ __forceinline__ unsigned pkt(float a, float b) {
  unsigned ua = __builtin_bit_cast(unsigned, a);
  unsigned ub = __builtin_bit_cast(unsigned, b);
  return (ua >> 16) | (ub & 0xffff0000u);
}
__device__ __forceinline__ float lo2f(unsigned p) { return __builtin_bit_cast(float, p << 16); }
__device__ __forceinline__ float hi2f(unsigned p) { return __builtin_bit_cast(float, p & 0xffff0000u); }

// split 8 fp32 -> 3 bf16x8 fragments (h1+h2+h3 capture >=23 mantissa bits)
__device__ __forceinline__ void split8(const float* f, U4& u1, U4& u2, U4& u3) {
#pragma unroll
  for (int i = 0; i < 4; ++i) {
    const float a = f[2 * i], b = f[2 * i + 1];
    const unsigned p1 = pkt(a, b);
    const float ra = a - lo2f(p1), rb = b - hi2f(p1);
    const unsigned p2 = pkt(ra, rb);
    const float sa = ra - lo2f(p2), sb = rb - hi2f(p2);
    u1.v[i] = p1; u2.v[i] = p2; u3.v[i] = pkt(sa, sb);
  }
}

// ------------------------------------------------------------------
// ws layout (floats):
//   [0, 393216)        Bpre: frag (kb32, j0, term, lane) -> bf16x8, 16 B each
//   [393216, 393280)   G[e] = sum_d gamma[d]*W[e][d]
//   [393280, 393344)   C[e] = sum_d beta[d]*W[e][d] + b[e]
//   [393344, 426112)   partials[NBLK][64]   (512 * 64)
// ------------------------------------------------------------------

__global__ __launch_bounds__(64) void prep_bpre(
    const float* __restrict__ W, const float* __restrict__ gamma,
    float* __restrict__ Bpre)
{
  const int b = blockIdx.x;            // 0..511
  const int kb32 = b >> 2, j0 = b & 3;
  const int L = threadIdx.x, q = L >> 4, c = L & 15;
  const int n  = j0 * 16 + c;          // expert
  const int k0 = kb32 * 32 + q * 8;    // k offset
  const float4 w0 = *(const float4*)(W + (size_t)n * D_MODEL + k0);
  const float4 w1 = *(const float4*)(W + (size_t)n * D_MODEL + k0 + 4);
  const float4 g0 = *(const float4*)(gamma + k0);
  const float4 g1 = *(const float4*)(gamma + k0 + 4);
  float f[8] = {w0.x * g0.x, w0.y * g0.y, w0.z * g0.z, w0.w * g0.w,
                w1.x * g1.x, w1.y * g1.y, w1.z * g1.z, w1.w * g1.w};
  U4 u1, u2, u3;
  split8(f, u1, u2, u3);
  const size_t base = ((size_t)kb32 * 12 + j0 * 3) * 64 + L;
  *(float4*)(Bpre + (base + 0 * 64) * 4) = __builtin_bit_cast(float4, u1);
  *(float4*)(Bpre + (base + 1 * 64) * 4) = __builtin_bit_cast(float4, u2);
  *(float4*)(Bpre + (base + 2 * 64) * 4) = __builtin_bit_cast(float4, u3);
}

__global__ __launch_bounds__(256) void prep_gc(
    const float* __restrict__ W, const float* __restrict__ gamma,
    const float* __restrict__ beta, const float* __restrict__ bias,
    float* __restrict__ G, float* __restrict__ C)
{
  const int e = blockIdx.x, t = threadIdx.x;
  float sg = 0.f, sb = 0.f;
#pragma unroll
  for (int i = 0; i < 4; ++i) {
    const int d = (i * 256 + t) * 4;
    const float4 wv = *(const float4*)(W + (size_t)e * D_MODEL + d);
    const float4 gv = *(const float4*)(gamma + d);
    const float4 bv = *(const float4*)(beta + d);
    sg += wv.x * gv.x + wv.y * gv.y + wv.z * gv.z + wv.w * gv.w;
    sb += wv.x * bv.x + wv.y * bv.y + wv.z * bv.z + wv.w * bv.w;
  }
#pragma unroll
  for (int o = 32; o > 0; o >>= 1) {
    sg += __shfl_xor(sg, o, 64);
    sb += __shfl_xor(sb, o, 64);
  }
  __shared__ float rg_[4], rb_[4];
  const int wid = t >> 6, ln = t & 63;
  if (ln == 0) { rg_[wid] = sg; rb_[wid] = sb; }
  __syncthreads();
  if (t == 0) {
    G[e] = rg_[0] + rg_[1] + rg_[2] + rg_[3];
    C[e] = rb_[0] + rb_[1] + rb_[2] + rb_[3] + bias[e];
  }
}

// async 16B global->LDS copy: global addr is per-lane, LDS dest is
// wave-uniform base + lane*16 (hardware lane scatter).
__device__ __forceinline__ void gload_lds16(const float* g, const float4* l) {
  __builtin_amdgcn_global_load_lds(
      (const __attribute__((address_space(1))) void*)(g),
      (__attribute__((address_space(3))) void*)(l),
      16, 0, 0);
}

// stage one BK=64 chunk (chunk nk covers kb32 {2nk, 2nk+1} = 24 frags, 24KB).
// All 4 waves stage 6 contiguous frags each.
__device__ __forceinline__ void stage24(const float* __restrict__ Bpre,
                                        float4* dst, int nk, int w, int L)
{
  const float* src = Bpre + (((size_t)nk * 24 + w * 6) * 64 + L) * 4;
  float4* d = dst + (size_t)(w * 6) * 64;   // wave-uniform base
#pragma unroll
  for (int i = 0; i < 6; ++i)
    gload_lds16(src + (size_t)i * 256, d + (size_t)i * 64);
}

// load this wave's A for step j (its kb32 = j*2+ks): k = (j*2+ks)*32 + q*8 + 0..7
__device__ __forceinline__ void loadA32(const float* aptr, int j, int ks, float4 A[2]) {
  const float* ap = aptr + (size_t)(j * 2 + ks) * 32;
  A[0] = *(const float4*)(ap);
  A[1] = *(const float4*)(ap + 4);
}

// one step: this wave consumes its kb32-half of the staged chunk:
// 12 ds_read_b128 + A split + 24 MFMA.
__device__ __forceinline__ void compute_step(
    const float4* __restrict__ buf, int ks, int L,
    const float4 A[2], f32x4 acc[4], float& Sp, float& Qp)
{
  const int PA[6] = {0, 0, 1, 0, 1, 2};
  const int PB[6] = {0, 1, 0, 2, 1, 0};
  s16x8 bf[4][3];
#pragma unroll
  for (int j0 = 0; j0 < 4; ++j0)
#pragma unroll
    for (int tt = 0; tt < 3; ++tt)
      bf[j0][tt] = __builtin_bit_cast(s16x8, buf[(size_t)(ks * 12 + j0 * 3 + tt) * 64 + L]);
  const float4 a0 = A[0], a1 = A[1];
  const float f[8] = {a0.x, a0.y, a0.z, a0.w, a1.x, a1.y, a1.z, a1.w};
#pragma unroll
  for (int i = 0; i < 8; ++i) { Sp += f[i]; Qp = fmaf(f[i], f[i], Qp); }
  U4 u1, u2, u3;
  split8(f, u1, u2, u3);
  const s16x8 af[3] = {__builtin_bit_cast(s16x8, u1),
                       __builtin_bit_cast(s16x8, u2),
                       __builtin_bit_cast(s16x8, u3)};
#pragma unroll
  for (int p = 0; p < 6; ++p)
#pragma unroll
    for (int j0 = 0; j0 < 4; ++j0)
      acc[j0] = __builtin_amdgcn_mfma_f32_16x16x32_bf16(af[PA[p]], bf[j0][PB[p]],
                                                        acc[j0], 0, 0, 0);
}

// 512 blocks x 4 waves (2 row-groups x 2 intra-chunk K-halves), 32 rows/block.
// ONE shared BK=64 double-buffered B stream per block (48KB LDS) -> 2
// independent blocks/CU: when one block stalls in its barrier drain, the
// other block's waves keep the LDS/MFMA/VALU pipes fed (the round-3/4
// lockstep had all waves in one barrier -> per-step latency paid serially).
__global__ __launch_bounds__(256, 2) void router_main(
    const float* __restrict__ x, const float* __restrict__ Bpre,
    const float* __restrict__ G, const float* __restrict__ C,
    float* __restrict__ out_sw, float* __restrict__ out_idx,
    float* __restrict__ out_partials, int k)
{
  const int t = threadIdx.x, w = t >> 6, L = t & 63;
  const int q = L >> 4, c = L & 15;
  const int g = w & 1;               // row-group (0..1)
  const int ks = w >> 1;             // K-half within each chunk (0..1)
  const int blk = blockIdx.x;
  const int row0 = blk * TMB + g * 16;

  // A-frag source (MFMA A layout): lane holds row row0+c, k-offsets q*8+0..7
  const float* aptr = x + (size_t)(row0 + c) * D_MODEL + q * 8;

  union Smem {
    float4 B[2][24 * 64];                          // 2 x 24KB double buffer
    struct { float red[2][64][19]; float sm[2][64]; } ep;
  };
  __shared__ Smem S;

  f32x4 acc[4];
#pragma unroll
  for (int j0 = 0; j0 < 4; ++j0) acc[j0] = (f32x4){0.f, 0.f, 0.f, 0.f};
  float Sp = 0.f, Qp = 0.f;

  float4 A0[2], A1[2];          // named buffers, ALL indices compile-time
  loadA32(aptr, 0, ks, A0);
  stage24(Bpre, S.B[0], 0, w, L);
  __syncthreads();              // drains stage(0) + A0

  for (int j = 0; j < NSTEP; j += 2) {
    // ---- even step j: compute B[0]/A0, stage chunk j+1 -> B[1], prefetch A1 ----
    stage24(Bpre, S.B[1], j + 1, w, L);
    loadA32(aptr, j + 1, ks, A1);
    compute_step(S.B[0], ks, L, A0, acc, Sp, Qp);
    __syncthreads();

    // ---- odd step j+1: compute B[1]/A1, stage chunk j+2 -> B[0], prefetch A0 ----
    if (j + 2 < NSTEP) stage24(Bpre, S.B[0], j + 2, w, L);
    loadA32(aptr, (j + 2) & (NSTEP - 1), ks, A0);   // dummy wrap (harmless)
    compute_step(S.B[1], ks, L, A1, acc, Sp, Qp);
    __syncthreads();
  }

  // ---- intra-wave LN partial reduce over the 4 lanes (q) sharing a row ----
#pragma unroll
  for (int o = 16; o <= 32; o <<= 1) {
    Sp += __shfl_xor(Sp, o, 64);
    Qp += __shfl_xor(Qp, o, 64);
  }

  // ---- cross-wave combine over the 2 K-halves (LDS, reusing B space) ----
  if (ks == 1) {
    float* dst = &S.ep.red[g][L][0];
#pragma unroll
    for (int j0 = 0; j0 < 4; ++j0)
#pragma unroll
      for (int i = 0; i < 4; ++i) dst[j0 * 4 + i] = acc[j0][i];
    dst[16] = Sp; dst[17] = Qp;
  }
  __syncthreads();

  if (ks == 0) {
    const float* sp_ = &S.ep.red[g][L][0];
#pragma unroll
    for (int j0 = 0; j0 < 4; ++j0)
#pragma unroll
      for (int i = 0; i < 4; ++i) acc[j0][i] += sp_[j0 * 4 + i];
    Sp += sp_[16]; Qp += sp_[17];

    const float mu = Sp * (1.f / D_MODEL);
    const float rs = rsqrtf(Qp * (1.f / D_MODEL) - mu * mu + LN_EPS);  // row row0+c

    float Gv[4], Cv[4];
#pragma unroll
    for (int j0 = 0; j0 < 4; ++j0) { Gv[j0] = G[16 * j0 + c]; Cv[j0] = C[16 * j0 + c]; }

    float mw[4] = {0.f, 0.f, 0.f, 0.f};
#pragma unroll
    for (int i = 0; i < 4; ++i) {          // C-layout: row = 4q+i, col = c
      const int rloc = 4 * q + i;
      const int row  = row0 + rloc;
      const float mui = __shfl(mu, rloc, 64);
      const float rsi = __shfl(rs, rloc, 64);
      float l[4];
#pragma unroll
      for (int j0 = 0; j0 < 4; ++j0)
        l[j0] = rsi * (acc[j0][i] - mui * Gv[j0]) + Cv[j0];
      float mx = fmaxf(fmaxf(l[0], l[1]), fmaxf(l[2], l[3]));
#pragma unroll
      for (int o = 1; o < 16; o <<= 1) mx = fmaxf(mx, __shfl_xor(mx, o, 64));
      float p[4], ss = 0.f;
#pragma unroll
      for (int j0 = 0; j0 < 4; ++j0) { p[j0] = __expf(l[j0] - mx); ss += p[j0]; }
#pragma unroll
      for (int o = 1; o < 16; o <<= 1) ss += __shfl_xor(ss, o, 64);
      float wv[4];
#pragma unroll
      for (int j0 = 0; j0 < 4; ++j0) { wv[j0] = p[j0] / ss; mw[j0] += wv[j0]; }

      // top-k (lowest-index tie-break, matches jax.lax.top_k)
      int ch[4];
      float denom = 0.f;
      for (int kk = 0; kk < k && kk < 4; ++kk) {
        float vb = -1.f; int eb = 1 << 30;
#pragma unroll
        for (int j0 = 0; j0 < 4; ++j0) {
          const int e = 16 * j0 + c;
          bool skip = false;
          for (int z = 0; z < kk; ++z) skip |= (ch[z] == e);
          const float cand = skip ? -1.f : wv[j0];
          if (cand > vb || (cand == vb && e < eb)) { vb = cand; eb = e; }
        }
#pragma unroll
        for (int o = 1; o < 16; o <<= 1) {
          const float ov = __shfl_xor(vb, o, 64);
          const int   oe = __shfl_xor(eb, o, 64);
          if (ov > vb || (ov == vb && oe < eb)) { vb = ov; eb = oe; }
        }
        ch[kk] = eb; denom += vb;
        if (c == 0) out_idx[(size_t)row * k + kk] = (float)eb;
      }
      denom += 1e-8f;
#pragma unroll
      for (int j0 = 0; j0 < 4; ++j0) {
        const int e = 16 * j0 + c;
        bool sel = false;
        for (int z = 0; z < k && z < 4; ++z) sel |= (ch[z] == e);
        out_sw[(size_t)row * N_EXP + e] = sel ? wv[j0] / denom : 0.f;
      }
    }

    // mean_w partials: sum over this group's 16 rows (xor over q)
#pragma unroll
    for (int j0 = 0; j0 < 4; ++j0)
#pragma unroll
      for (int o = 16; o <= 32; o <<= 1) mw[j0] += __shfl_xor(mw[j0], o, 64);
    if (q == 0) {
#pragma unroll
      for (int j0 = 0; j0 < 4; ++j0) S.ep.sm[g][16 * j0 + c] = mw[j0];
    }
  }
  __syncthreads();
  if (t < 64)
    out_partials[blk * 64 + t] = S.ep.sm[0][t] + S.ep.sm[1][t];
}

__global__ __launch_bounds__(256) void loss_kernel(
    const float* __restrict__ partials, float* __restrict__ out_loss)
{
  const int t = threadIdx.x, e = t & 63, qq = t >> 6;
  float s = 0.f;
#pragma unroll 8
  for (int b = 0; b < 128; ++b) s += partials[(qq * 128 + b) * 64 + e];
  __shared__ float sh[256];
  sh[t] = s;
  __syncthreads();
  if (t < 64) {
    const float m = (sh[t] + sh[64 + t] + sh[128 + t] + sh[192 + t]) * (1.f / N_ROWS);
    float v = -m * logf(m + 1e-8f);
#pragma unroll
    for (int o = 32; o > 0; o >>= 1) v += __shfl_xor(v, o, 64);
    if (t == 0) out_loss[0] = v;
  }
}

extern "C" void kernel_launch(void* const* d_in, const int* in_sizes, int n_in,
                              void* d_out, int out_size, void* d_ws, size_t ws_size,
                              hipStream_t stream)
{
  const float* x     = (const float*)d_in[0];
  const float* gamma = (const float*)d_in[1];
  const float* beta  = (const float*)d_in[2];
  const float* W     = (const float*)d_in[3];
  const float* bias  = (const float*)d_in[4];

  float* ws       = (float*)d_ws;
  float* Bpre     = ws;
  float* G        = ws + 393216;
  float* C        = ws + 393280;
  float* partials = ws + 393344;   // NBLK*64 = 32768 floats

  int k = (out_size - N_ROWS * N_EXP - 1) / N_ROWS;
  if (k < 1) k = 1;
  if (k > 4) k = 4;

  float* out      = (float*)d_out;
  float* out_sw   = out;
  float* out_idx  = out + (size_t)N_ROWS * N_EXP;
  float* out_loss = out + (size_t)N_ROWS * N_EXP + (size_t)N_ROWS * k;

  hipLaunchKernelGGL(prep_bpre, dim3(512), dim3(64), 0, stream, W, gamma, Bpre);
  hipLaunchKernelGGL(prep_gc, dim3(N_EXP), dim3(256), 0, stream, W, gamma, beta, bias, G, C);
  hipLaunchKernelGGL(router_main, dim3(NBLK), dim3(256), 0, stream,
                     x, Bpre, G, C, out_sw, out_idx, partials, k);
  hipLaunchKernelGGL(loss_kernel, dim3(1), dim3(256), 0, stream, partials, out_loss);
}

// Round 7
// 417.895 us; speedup vs baseline: 1.0146x; 1.0146x over previous
//
#include <hip/hip_runtime.h>
#include <math.h>

#define D_MODEL 4096
#define N_EXP   64
#define N_ROWS  16384            // 4 * 4096
#define LN_EPS  1e-5f
#define TMB     64               // rows per block (4 row-groups of 16)
#define NBLK    (N_ROWS / TMB)   // 256 blocks = 1 per CU
#define NSTEP   64               // K steps of BK=64

typedef __attribute__((ext_vector_type(4))) float f32x4;
typedef __attribute__((ext_vector_type(8))) short s16x8;

struct U4 { unsigned v[4]; };

// truncating bf16 split helpers: pkt packs hi16(a) | hi16(b); residuals are exact.
__device__ __forceinline__ unsigned pkt(float a, float b) {
  unsigned ua = __builtin_bit_cast(unsigned, a);
  unsigned ub = __builtin_bit_cast(unsigned, b);
  return (ua >> 16) | (ub & 0xffff0000u);
}
__device__ __forceinline__ float lo2f(unsigned p) { return __builtin_bit_cast(float, p << 16); }
__device__ __forceinline__ float hi2f(unsigned p) { return __builtin_bit_cast(float, p & 0xffff0000u); }

// split 8 fp32 -> 3 bf16x8 fragments (h1+h2+h3 capture >=23 mantissa bits)
__device__ __forceinline__ void split8(const float* f, U4& u1, U4& u2, U4& u3) {
#pragma unroll
  for (int i = 0; i < 4; ++i) {
    const float a = f[2 * i], b = f[2 * i + 1];
    const unsigned p1 = pkt(a, b);
    const float ra = a - lo2f(p1), rb = b - hi2f(p1);
    const unsigned p2 = pkt(ra, rb);
    const float sa = ra - lo2f(p2), sb = rb - hi2f(p2);
    u1.v[i] = p1; u2.v[i] = p2; u3.v[i] = pkt(sa, sb);
  }
}

// ------------------------------------------------------------------
// ws layout (floats):
//   [0, 393216)        Bpre: frag (kb32, j0, term, lane) -> bf16x8, 16 B each
//   [393216, 393280)   G[e] = sum_d gamma[d]*W[e][d]
//   [393280, 393344)   C[e] = sum_d beta[d]*W[e][d] + b[e]
//   [393344, 409728)   partials[NBLK][64]   (256 * 64)
// ------------------------------------------------------------------

__global__ __launch_bounds__(64) void prep_bpre(
    const float* __restrict__ W, const float* __restrict__ gamma,
    float* __restrict__ Bpre)
{
  const int b = blockIdx.x;            // 0..511
  const int kb32 = b >> 2, j0 = b & 3;
  const int L = threadIdx.x, q = L >> 4, c = L & 15;
  const int n  = j0 * 16 + c;          // expert
  const int k0 = kb32 * 32 + q * 8;    // k offset
  const float4 w0 = *(const float4*)(W + (size_t)n * D_MODEL + k0);
  const float4 w1 = *(const float4*)(W + (size_t)n * D_MODEL + k0 + 4);
  const float4 g0 = *(const float4*)(gamma + k0);
  const float4 g1 = *(const float4*)(gamma + k0 + 4);
  float f[8] = {w0.x * g0.x, w0.y * g0.y, w0.z * g0.z, w0.w * g0.w,
                w1.x * g1.x, w1.y * g1.y, w1.z * g1.z, w1.w * g1.w};
  U4 u1, u2, u3;
  split8(f, u1, u2, u3);
  const size_t base = ((size_t)kb32 * 12 + j0 * 3) * 64 + L;
  *(float4*)(Bpre + (base + 0 * 64) * 4) = __builtin_bit_cast(float4, u1);
  *(float4*)(Bpre + (base + 1 * 64) * 4) = __builtin_bit_cast(float4, u2);
  *(float4*)(Bpre + (base + 2 * 64) * 4) = __builtin_bit_cast(float4, u3);
}

__global__ __launch_bounds__(256) void prep_gc(
    const float* __restrict__ W, const float* __restrict__ gamma,
    const float* __restrict__ beta, const float* __restrict__ bias,
    float* __restrict__ G, float* __restrict__ C)
{
  const int e = blockIdx.x, t = threadIdx.x;
  float sg = 0.f, sb = 0.f;
#pragma unroll
  for (int i = 0; i < 4; ++i) {
    const int d = (i * 256 + t) * 4;
    const float4 wv = *(const float4*)(W + (size_t)e * D_MODEL + d);
    const float4 gv = *(const float4*)(gamma + d);
    const float4 bv = *(const float4*)(beta + d);
    sg += wv.x * gv.x + wv.y * gv.y + wv.z * gv.z + wv.w * gv.w;
    sb += wv.x * bv.x + wv.y * bv.y + wv.z * bv.z + wv.w * bv.w;
  }
#pragma unroll
  for (int o = 32; o > 0; o >>= 1) {
    sg += __shfl_xor(sg, o, 64);
    sb += __shfl_xor(sb, o, 64);
  }
  __shared__ float rg_[4], rb_[4];
  const int wid = t >> 6, ln = t & 63;
  if (ln == 0) { rg_[wid] = sg; rb_[wid] = sb; }
  __syncthreads();
  if (t == 0) {
    G[e] = rg_[0] + rg_[1] + rg_[2] + rg_[3];
    C[e] = rb_[0] + rb_[1] + rb_[2] + rb_[3] + bias[e];
  }
}

// async 16B global->LDS copy: global addr is per-lane, LDS dest is
// wave-uniform base + lane*16 (hardware lane scatter).
__device__ __forceinline__ void gload_lds16(const float* g, const float4* l) {
  __builtin_amdgcn_global_load_lds(
      (const __attribute__((address_space(1))) void*)(g),
      (__attribute__((address_space(3))) void*)(l),
      16, 0, 0);
}

// stage this wave's share (3 frags) of one BK=64 chunk (24 frags, 24KB).
// Chunk nk covers kb32 {2nk, 2nk+1}; wave w stages frags w*3..w*3+2.
// Exactly 3 VMEM instructions -- the counted-vmcnt schedule depends on this.
__device__ __forceinline__ void stage3(const float* __restrict__ Bpre,
                                       float4* dst, int nk, int w, int L)
{
  const float* src = Bpre + (((size_t)nk * 24 + w * 3) * 64 + L) * 4;
  float4* d = dst + (size_t)(w * 3) * 64;   // wave-uniform base
#pragma unroll
  for (int i = 0; i < 3; ++i)
    gload_lds16(src + (size_t)i * 256, d + (size_t)i * 64);
}

// load this wave's A for chunk nk (its kb32 = nk*2+ks): 2 VMEM instructions.
__device__ __forceinline__ void loadA32(const float* aptr, int nk, int ks, float4 A[2]) {
  const float* ap = aptr + (size_t)(nk * 2 + ks) * 32;
  A[0] = *(const float4*)(ap);
  A[1] = *(const float4*)(ap + 4);
}

// one step: this wave consumes its kb32-half of the staged chunk:
// 12 ds_read_b128 + A split + 24 MFMA.
__device__ __forceinline__ void compute_step(
    const float4* __restrict__ buf, int ks, int L,
    const float4 A[2], f32x4 acc[4], float& Sp, float& Qp)
{
  const int PA[6] = {0, 0, 1, 0, 1, 2};
  const int PB[6] = {0, 1, 0, 2, 1, 0};
  s16x8 bf[4][3];
#pragma unroll
  for (int j0 = 0; j0 < 4; ++j0)
#pragma unroll
    for (int tt = 0; tt < 3; ++tt)
      bf[j0][tt] = __builtin_bit_cast(s16x8, buf[(size_t)(ks * 12 + j0 * 3 + tt) * 64 + L]);
  const float4 a0 = A[0], a1 = A[1];
  const float f[8] = {a0.x, a0.y, a0.z, a0.w, a1.x, a1.y, a1.z, a1.w};
#pragma unroll
  for (int i = 0; i < 8; ++i) { Sp += f[i]; Qp = fmaf(f[i], f[i], Qp); }
  U4 u1, u2, u3;
  split8(f, u1, u2, u3);
  const s16x8 af[3] = {__builtin_bit_cast(s16x8, u1),
                       __builtin_bit_cast(s16x8, u2),
                       __builtin_bit_cast(s16x8, u3)};
#pragma unroll
  for (int p = 0; p < 6; ++p)
#pragma unroll
    for (int j0 = 0; j0 < 4; ++j0)
      acc[j0] = __builtin_amdgcn_mfma_f32_16x16x32_bf16(af[PA[p]], bf[j0][PB[p]],
                                                        acc[j0], 0, 0, 0);
}

// T3/T4 counted-vmcnt schedule: each step = {s_waitcnt vmcnt(5); raw
// s_barrier; stage chunk j+2 (3 gload_lds); load A(j+1) (2 VMEM); compute
// chunk j from the 3-deep LDS ring}. 5 VMEM ops/wave/step, so vmcnt(5) at
// step top == "everything issued before the previous step retired" == chunk
// j staged; the barrier makes it cross-wave. The pipe is NEVER drained to 0
// inside the loop (rounds 3-5 drained 2x/step via __syncthreads -- the
// invariant ~147us across all TLP variants). WAR on the ring: buf (j+2)%3
// was last read at step j-1, which every wave finished before this barrier.
__global__ __launch_bounds__(512, 2) void router_main(
    const float* __restrict__ x, const float* __restrict__ Bpre,
    const float* __restrict__ G, const float* __restrict__ C,
    float* __restrict__ out_sw, float* __restrict__ out_idx,
    float* __restrict__ out_partials, int k)
{
  const int t = threadIdx.x, w = t >> 6, L = t & 63;
  const int q = L >> 4, c = L & 15;
  const int g = w & 3;               // row-group (0..3)
  const int ks = w >> 2;             // K-half within each chunk (0..1)
  const int blk = blockIdx.x;
  const int row0 = blk * TMB + g * 16;

  // A-frag source (MFMA A layout): lane holds row row0+c, k-offsets q*8+0..7
  const float* aptr = x + (size_t)(row0 + c) * D_MODEL + q * 8;

  union Smem {
    float4 B[3][24 * 64];                          // 3 x 24KB ring
    struct { float red[4][64][19]; float sm[4][64]; } ep;
  };
  __shared__ Smem S;

  f32x4 acc[4];
#pragma unroll
  for (int j0 = 0; j0 < 4; ++j0) acc[j0] = (f32x4){0.f, 0.f, 0.f, 0.f};
  float Sp = 0.f, Qp = 0.f;

  float4 A0[2], A1[2];          // named buffers, ALL indices compile-time

  // prologue: stage chunk0 (3), A0 (2), stage chunk1 (3) -> 8 outstanding
  stage3(Bpre, &S.B[0][0], 0, w, L);
  loadA32(aptr, 0, ks, A0);
  stage3(Bpre, &S.B[1][0], 1, w, L);

#define STEP_BODY(J, BC, AC, AN)                                          \
  {                                                                       \
    asm volatile("s_waitcnt vmcnt(5)" ::: "memory");                      \
    __builtin_amdgcn_s_barrier();                                         \
    asm volatile("" ::: "memory");                                        \
    __builtin_amdgcn_sched_barrier(0);                                    \
    const int bs_ = (BC) ? (BC) - 1 : 2;      /* == (BC+2)%3 */           \
    stage3(Bpre, &S.B[bs_][0], ((J) + 2) & (NSTEP - 1), w, L);            \
    loadA32(aptr, ((J) + 1) & (NSTEP - 1), ks, AN);                       \
    compute_step(&S.B[BC][0], ks, L, AC, acc, Sp, Qp);                    \
  }

  int bc = 0;
  for (int j = 0; j < NSTEP; j += 2) {
    STEP_BODY(j,     bc, A0, A1);
    bc = (bc == 2) ? 0 : bc + 1;
    STEP_BODY(j + 1, bc, A1, A0);
    bc = (bc == 2) ? 0 : bc + 1;
  }
#undef STEP_BODY

  __syncthreads();   // full drain (incl. tail dummy stages) before LDS reuse

  // ---- intra-wave LN partial reduce over the 4 lanes (q) sharing a row ----
#pragma unroll
  for (int o = 16; o <= 32; o <<= 1) {
    Sp += __shfl_xor(Sp, o, 64);
    Qp += __shfl_xor(Qp, o, 64);
  }

  // ---- cross-wave combine over the 2 K-halves (LDS, reusing B space) ----
  if (ks == 1) {
    float* dst = &S.ep.red[g][L][0];
#pragma unroll
    for (int j0 = 0; j0 < 4; ++j0)
#pragma unroll
      for (int i = 0; i < 4; ++i) dst[j0 * 4 + i] = acc[j0][i];
    dst[16] = Sp; dst[17] = Qp;
  }
  __syncthreads();

  if (ks == 0) {
    const float* sp_ = &S.ep.red[g][L][0];
#pragma unroll
    for (int j0 = 0; j0 < 4; ++j0)
#pragma unroll
      for (int i = 0; i < 4; ++i) acc[j0][i] += sp_[j0 * 4 + i];
    Sp += sp_[16]; Qp += sp_[17];

    const float mu = Sp * (1.f / D_MODEL);
    const float rs = rsqrtf(Qp * (1.f / D_MODEL) - mu * mu + LN_EPS);  // row row0+c

    float Gv[4], Cv[4];
#pragma unroll
    for (int j0 = 0; j0 < 4; ++j0) { Gv[j0] = G[16 * j0 + c]; Cv[j0] = C[16 * j0 + c]; }

    float mw[4] = {0.f, 0.f, 0.f, 0.f};
#pragma unroll
    for (int i = 0; i < 4; ++i) {          // C-layout: row = 4q+i, col = c
      const int rloc = 4 * q + i;
      const int row  = row0 + rloc;
      const float mui = __shfl(mu, rloc, 64);
      const float rsi = __shfl(rs, rloc, 64);
      float l[4];
#pragma unroll
      for (int j0 = 0; j0 < 4; ++j0)
        l[j0] = rsi * (acc[j0][i] - mui * Gv[j0]) + Cv[j0];
      float mx = fmaxf(fmaxf(l[0], l[1]), fmaxf(l[2], l[3]));
#pragma unroll
      for (int o = 1; o < 16; o <<= 1) mx = fmaxf(mx, __shfl_xor(mx, o, 64));
      float p[4], ss = 0.f;
#pragma unroll
      for (int j0 = 0; j0 < 4; ++j0) { p[j0] = __expf(l[j0] - mx); ss += p[j0]; }
#pragma unroll
      for (int o = 1; o < 16; o <<= 1) ss += __shfl_xor(ss, o, 64);
      float wv[4];
#pragma unroll
      for (int j0 = 0; j0 < 4; ++j0) { wv[j0] = p[j0] / ss; mw[j0] += wv[j0]; }

      // top-k (lowest-index tie-break, matches jax.lax.top_k)
      int ch[4];
      float denom = 0.f;
      for (int kk = 0; kk < k && kk < 4; ++kk) {
        float vb = -1.f; int eb = 1 << 30;
#pragma unroll
        for (int j0 = 0; j0 < 4; ++j0) {
          const int e = 16 * j0 + c;
          bool skip = false;
          for (int z = 0; z < kk; ++z) skip |= (ch[z] == e);
          const float cand = skip ? -1.f : wv[j0];
          if (cand > vb || (cand == vb && e < eb)) { vb = cand; eb = e; }
        }
#pragma unroll
        for (int o = 1; o < 16; o <<= 1) {
          const float ov = __shfl_xor(vb, o, 64);
          const int   oe = __shfl_xor(eb, o, 64);
          if (ov > vb || (ov == vb && oe < eb)) { vb = ov; eb = oe; }
        }
        ch[kk] = eb; denom += vb;
        if (c == 0) out_idx[(size_t)row * k + kk] = (float)eb;
      }
      denom += 1e-8f;
#pragma unroll
      for (int j0 = 0; j0 < 4; ++j0) {
        const int e = 16 * j0 + c;
        bool sel = false;
        for (int z = 0; z < k && z < 4; ++z) sel |= (ch[z] == e);
        out_sw[(size_t)row * N_EXP + e] = sel ? wv[j0] / denom : 0.f;
      }
    }

    // mean_w partials: sum over this group's 16 rows (xor over q)
#pragma unroll
    for (int j0 = 0; j0 < 4; ++j0)
#pragma unroll
      for (int o = 16; o <= 32; o <<= 1) mw[j0] += __shfl_xor(mw[j0], o, 64);
    if (q == 0) {
#pragma unroll
      for (int j0 = 0; j0 < 4; ++j0) S.ep.sm[g][16 * j0 + c] = mw[j0];
    }
  }
  __syncthreads();
  if (t < 64)
    out_partials[blk * 64 + t] = S.ep.sm[0][t] + S.ep.sm[1][t] + S.ep.sm[2][t] + S.ep.sm[3][t];
}

__global__ __launch_bounds__(256) void loss_kernel(
    const float* __restrict__ partials, float* __restrict__ out_loss)
{
  const int t = threadIdx.x, e = t & 63, qq = t >> 6;
  float s = 0.f;
#pragma unroll 8
  for (int b = 0; b < 64; ++b) s += partials[(qq * 64 + b) * 64 + e];
  __shared__ float sh[256];
  sh[t] = s;
  __syncthreads();
  if (t < 64) {
    const float m = (sh[t] + sh[64 + t] + sh[128 + t] + sh[192 + t]) * (1.f / N_ROWS);
    float v = -m * logf(m + 1e-8f);
#pragma unroll
    for (int o = 32; o > 0; o >>= 1) v += __shfl_xor(v, o, 64);
    if (t == 0) out_loss[0] = v;
  }
}

extern "C" void kernel_launch(void* const* d_in, const int* in_sizes, int n_in,
                              void* d_out, int out_size, void* d_ws, size_t ws_size,
                              hipStream_t stream)
{
  const float* x     = (const float*)d_in[0];
  const float* gamma = (const float*)d_in[1];
  const float* beta  = (const float*)d_in[2];
  const float* W     = (const float*)d_in[3];
  const float* bias  = (const float*)d_in[4];

  float* ws       = (float*)d_ws;
  float* Bpre     = ws;
  float* G        = ws + 393216;
  float* C        = ws + 393280;
  float* partials = ws + 393344;   // NBLK*64 = 16384 floats

  int k = (out_size - N_ROWS * N_EXP - 1) / N_ROWS;
  if (k < 1) k = 1;
  if (k > 4) k = 4;

  float* out      = (float*)d_out;
  float* out_sw   = out;
  float* out_idx  = out + (size_t)N_ROWS * N_EXP;
  float* out_loss = out + (size_t)N_ROWS * N_EXP + (size_t)N_ROWS * k;

  hipLaunchKernelGGL(prep_bpre, dim3(512), dim3(64), 0, stream, W, gamma, Bpre);
  hipLaunchKernelGGL(prep_gc, dim3(N_EXP), dim3(256), 0, stream, W, gamma, beta, bias, G, C);
  hipLaunchKernelGGL(router_main, dim3(NBLK), dim3(512), 0, stream,
                     x, Bpre, G, C, out_sw, out_idx, partials, k);
  hipLaunchKernelGGL(loss_kernel, dim3(1), dim3(256), 0, stream, partials, out_loss);
}